// Round 5
// baseline (394.936 us; speedup 1.0000x reference)
//
#include <hip/hip_runtime.h>
#include <hip/hip_bf16.h>

// Attention_2241972929086 — round 4: attn v4 (128-q blocks, double-buffered K/V,
// exp2 softmax, pk_bf16 P-pack) + row-major Q/K/V layout + fused W conversions.
// B=4 S=2048 D=1024 H=16 d=64.
// ws (bf16): Q[B,S,1024](prescaled x0.125*log2e) | K[B,S,1024] | V[B,S,1024] |
//            {Xbf -> Aout}[B,S,1024].  WoT overwrites Q slot AFTER attn.
// d_out temp: mp 512KB | WcatT 6MB @ +0.5MB | V^T 16MB @ +8MB — dead before out_mfma.

using bf16 = __hip_bfloat16;
typedef __attribute__((ext_vector_type(8))) short short8;
typedef __attribute__((ext_vector_type(4))) float floatx4;

#define kB 4
#define kS 2048
#define kDM 1024
#define kH 16
#define kDH 64
#define kHeadElems ((size_t)kB * kH * kS * kDH)   /* 8388608 */
#define STR 72
#define kQScale 0.1803368801f   /* 0.125 * log2(e): softmax via exp2 */

__device__ __forceinline__ unsigned short f2bf(float f) {
    union { float f; unsigned u; } x{f};
    unsigned r = x.u + 0x7fff + ((x.u >> 16) & 1);
    return (unsigned short)(r >> 16);
}
__device__ __forceinline__ void gl_lds16(const void* g, void* l) {
    __builtin_amdgcn_global_load_lds(
        (const __attribute__((address_space(1))) unsigned int*)g,
        (__attribute__((address_space(3))) unsigned int*)l, 16, 0, 0);
}

// ---------------------------------------------------------------------------
// pack_mask: bitmask [S][32] u64; bit = mask_aft[q][key] || key>q.
// ---------------------------------------------------------------------------
__global__ __launch_bounds__(256)
void pack_mask(const int* __restrict__ mask_aft, unsigned long long* __restrict__ mp)
{
    const int widx = blockIdx.x * 4 + (threadIdx.x >> 6);
    const int lane = threadIdx.x & 63;
    const int q = widx >> 5, w64 = widx & 31;
    const int key = w64 * 64 + lane;
    const int m = mask_aft[(size_t)q * kS + key];
    const unsigned long long b = __ballot(m != 0 || key > q);
    if (lane == 0) mp[widx] = b;
}

// ---------------------------------------------------------------------------
// conv_x: fp32 -> bf16 cast, 8 elems/thread.
// ---------------------------------------------------------------------------
__global__ __launch_bounds__(256)
void conv_x(const float* __restrict__ X, bf16* __restrict__ Xb)
{
    const size_t i = ((size_t)blockIdx.x * 256 + threadIdx.x) * 8;
    const float4 a = *(const float4*)(X + i);
    const float4 b = *(const float4*)(X + i + 4);
    union { unsigned short u[8]; uint4 v; } o;
    o.u[0] = f2bf(a.x); o.u[1] = f2bf(a.y); o.u[2] = f2bf(a.z); o.u[3] = f2bf(a.w);
    o.u[4] = f2bf(b.x); o.u[5] = f2bf(b.y); o.u[6] = f2bf(b.z); o.u[7] = f2bf(b.w);
    *(uint4*)(Xb + i) = o.v;
}

// ---------------------------------------------------------------------------
// conv_wT body: W [1024][1024] fp32 -> W^T bf16 (shared by conv_w3 / conv_wT).
// ---------------------------------------------------------------------------
__device__ __forceinline__ void conv_wT_body(const float* __restrict__ W,
                                             bf16* __restrict__ WT)
{
    __shared__ unsigned short Ls[64][STR];
    const int k0 = blockIdx.x * 64, n0 = blockIdx.y * 64;
    const int tid = threadIdx.x;
    const int r16 = tid >> 4, c4 = (tid & 15) * 4;
    #pragma unroll
    for (int it = 0; it < 4; ++it) {
        const int r = it * 16 + r16;
        const float4 v = *(const float4*)(W + (size_t)(k0 + r) * kDM + n0 + c4);
        Ls[c4 + 0][r] = f2bf(v.x); Ls[c4 + 1][r] = f2bf(v.y);
        Ls[c4 + 2][r] = f2bf(v.z); Ls[c4 + 3][r] = f2bf(v.w);
    }
    __syncthreads();
    #pragma unroll
    for (int it = 0; it < 4; ++it) {
        const int rn = it * 16 + r16;
        ushort4 u;
        u.x = Ls[rn][c4 + 0]; u.y = Ls[rn][c4 + 1];
        u.z = Ls[rn][c4 + 2]; u.w = Ls[rn][c4 + 3];
        *(ushort4*)(WT + (size_t)(n0 + rn) * kDM + k0 + c4) = u;
    }
}

__global__ __launch_bounds__(256)
void conv_w3(const float* __restrict__ Wq, const float* __restrict__ Wk,
             const float* __restrict__ Wv, bf16* __restrict__ WT)
{
    const int z = blockIdx.z;
    const float* W = (z == 0) ? Wq : ((z == 1) ? Wk : Wv);
    conv_wT_body(W, WT + (size_t)z * kDM * kDM);
}

__global__ __launch_bounds__(256)
void conv_wT(const float* __restrict__ W, bf16* __restrict__ WT)
{
    conv_wT_body(W, WT);
}

// ---------------------------------------------------------------------------
// qkv_mfma: Xbf[8192][1024] @ WcatT[3072][1024]^T -> Q/K/V each [B,S,1024] bf16
// (row-major GEMM C layout; head h occupies cols h*64..h*64+63).
// Q pre-scaled by 0.125*log2(e).  grid (24, 64), block 256.
// ---------------------------------------------------------------------------
__global__ __launch_bounds__(256)
void qkv_mfma(const bf16* __restrict__ A, const bf16* __restrict__ BT,
              bf16* __restrict__ ws)
{
    __shared__ __align__(16) unsigned short At[128][32];
    __shared__ __align__(16) unsigned short Bt[128][32];
    const int tid = threadIdx.x;
    const int w = tid >> 6, lane = tid & 63;
    const int quad = (tid >> 4) & 3, col = tid & 15;
    const int wm = w >> 1, wn = w & 1;
    const int n0 = blockIdx.x * 128;
    const int m0 = blockIdx.y * 128;

    const bf16* pA = A  + (size_t)(m0 + w * 32 + (lane >> 2)) * kDM + (lane & 3) * 8;
    const bf16* pB = BT + (size_t)(n0 + w * 32 + (lane >> 2)) * kDM + (lane & 3) * 8;
    unsigned short* lA = &At[w * 32][0];
    unsigned short* lB = &Bt[w * 32][0];

    floatx4 acc[4][4];
    #pragma unroll
    for (int i = 0; i < 4; ++i)
        #pragma unroll
        for (int j = 0; j < 4; ++j) acc[i][j] = (floatx4){0.f, 0.f, 0.f, 0.f};

    for (int k0 = 0; k0 < kDM; k0 += 32) {
        __syncthreads();
        gl_lds16(pA + k0, lA);
        gl_lds16(pA + k0 + 16 * kDM, lA + 16 * 32);
        gl_lds16(pB + k0, lB);
        gl_lds16(pB + k0 + 16 * kDM, lB + 16 * 32);
        __syncthreads();
        short8 aA[4], bB[4];
        #pragma unroll
        for (int i = 0; i < 4; ++i)
            aA[i] = *(const short8*)&At[wm * 64 + i * 16 + col][quad * 8];
        #pragma unroll
        for (int j = 0; j < 4; ++j)
            bB[j] = *(const short8*)&Bt[wn * 64 + j * 16 + col][quad * 8];
        #pragma unroll
        for (int i = 0; i < 4; ++i)
            #pragma unroll
            for (int j = 0; j < 4; ++j)
                acc[i][j] = __builtin_amdgcn_mfma_f32_16x16x32_bf16(aA[i], bB[j], acc[i][j], 0, 0, 0);
    }

    const int p   = n0 >> 10;
    const int nn0 = n0 & 1023;
    const float scl = (p == 0) ? kQScale : 1.0f;
    bf16* Out = ws + (size_t)p * kHeadElems;
    #pragma unroll
    for (int i = 0; i < 4; ++i) {
        #pragma unroll
        for (int r = 0; r < 4; ++r) {
            const int m = m0 + wm * 64 + i * 16 + quad * 4 + r;
            bf16* base = Out + (size_t)m * kDM + nn0 + wn * 64 + col;
            #pragma unroll
            for (int j = 0; j < 4; ++j)
                base[j * 16] = __float2bfloat16(acc[i][j][r] * scl);
        }
    }
}

// ---------------------------------------------------------------------------
// vtrans: V [B,S,1024] (head h cols) -> V^T [bh][64][2048]. grid (32, 64).
// ---------------------------------------------------------------------------
__global__ __launch_bounds__(256)
void vtrans(const bf16* __restrict__ V, bf16* __restrict__ VT)
{
    const int bh = blockIdx.y;
    const int b = bh >> 4, h = bh & 15;
    const int s0 = blockIdx.x * 64;
    const bf16* src = V + ((size_t)b * kS) * kDM + h * kDH;
    bf16* dst = VT + (size_t)bh * kS * kDH;
    __shared__ unsigned short L[64][STR];
    const int tid = threadIdx.x;
    #pragma unroll
    for (int t = 0; t < 2; ++t) {
        const int idx = t * 256 + tid;
        const int r = idx >> 3, c8 = (idx & 7) * 8;
        *(uint4*)&L[r][c8] = *(const uint4*)(src + (size_t)(s0 + r) * kDM + c8);
    }
    __syncthreads();
    #pragma unroll
    for (int t = 0; t < 2; ++t) {
        const int idx = t * 256 + tid;
        const int d = idx >> 3, sc = (idx & 7) * 8;
        unsigned short tmp[8];
        #pragma unroll
        for (int e = 0; e < 8; ++e) tmp[e] = L[sc + e][d];
        *(uint4*)(dst + (size_t)d * kS + s0 + sc) = *(uint4*)tmp;
    }
}

// ---------------------------------------------------------------------------
// attn_mfma v4: grid (16 qtiles, 64 bh), block 256 = 4 waves x 32 q (2x16 subgroups).
// 128-q blocks, double-buffered 64-key K/V LDS tiles (gl_lds prefetch overlaps
// compute), S^T MFMA, exp2 softmax (scale pre-folded), pk_bf16 P pack.
// ---------------------------------------------------------------------------
__global__ __launch_bounds__(256, 3)
void attn_mfma(const bf16* __restrict__ Qb, const bf16* __restrict__ Kb,
               const bf16* __restrict__ VT, const unsigned long long* __restrict__ mp,
               bf16* __restrict__ Aout)
{
    const int bh = blockIdx.y;
    const int b = bh >> 4, h = bh & 15;
    const int qtile = 15 - blockIdx.x;          // heavy blocks first
    const int q0 = qtile * 128;
    const int tid = threadIdx.x;
    const int w    = tid >> 6;
    const int lane = tid & 63;
    const int quad = (tid >> 4) & 3;
    const int col  = tid & 15;

    const bf16* Qg  = Qb + ((size_t)b * kS) * kDM + h * kDH;   // row q at +q*1024
    const bf16* Kg  = Kb + ((size_t)b * kS) * kDM + h * kDH;
    const bf16* VTg = VT + (size_t)bh * kS * kDH;              // [64 d][2048 s]

    __shared__ __align__(16) unsigned short Ks[2][64][64];     // dbuf K tiles
    __shared__ __align__(16) unsigned short Vs[2][64][64];     // dbuf V^T tiles
    __shared__ __align__(16) unsigned short Pw[4][16][STR];    // per-wave P staging
    __shared__ unsigned long long Mw[2][128];                  // dbuf mask words

    const int swz = col & 7;
    const int sch = (lane & 7) ^ (lane >> 3);

    // Q B-fragments for both 16-q subgroups (Q pre-scaled by 0.125*log2e)
    short8 bQ[2][2];
    #pragma unroll
    for (int qg = 0; qg < 2; ++qg) {
        const int qr = q0 + w * 32 + qg * 16 + col;
        bQ[qg][0] = *(const short8*)(Qg + (size_t)qr * kDM + quad * 8);
        bQ[qg][1] = *(const short8*)(Qg + (size_t)qr * kDM + 32 + quad * 8);
    }

    floatx4 Ov[2][4];
    #pragma unroll
    for (int qg = 0; qg < 2; ++qg)
        #pragma unroll
        for (int dg = 0; dg < 4; ++dg) Ov[qg][dg] = (floatx4){0.f, 0.f, 0.f, 0.f};
    float lacc[2] = {0.f, 0.f};

    const int nkt = 2 * qtile + 2;

    auto stage = [&](int kt, int buf) {
        #pragma unroll
        for (int t = 0; t < 2; ++t) {
            const int rbase = (t * 4 + w) * 8;
            const int r = rbase + (lane >> 3);
            gl_lds16(Kg  + (size_t)(kt * 64 + r) * kDM + sch * 8, &Ks[buf][rbase][0]);
            gl_lds16(VTg + (size_t)r * kS + kt * 64 + sch * 8,    &Vs[buf][rbase][0]);
        }
        if (tid < 128) Mw[buf][tid] = mp[(size_t)(q0 + tid) * 32 + kt];
    };

    stage(0, 0);

    for (int kt = 0; kt < nkt; ++kt) {
        const int cur = kt & 1;
        __syncthreads();                         // staged data for kt now visible
        if (kt + 1 < nkt) stage(kt + 1, cur ^ 1);   // prefetch overlaps compute

        if (kt * 64 > q0 + w * 32 + 31) continue;   // whole wave future of this tile

        // K A-fragments (shared across both q subgroups)
        short8 aK[4][2];
        #pragma unroll
        for (int g = 0; g < 4; ++g) {
            const int krow = g * 16 + col;
            aK[g][0] = *(const short8*)&Ks[cur][krow][(quad ^ swz) * 8];
            aK[g][1] = *(const short8*)&Ks[cur][krow][((4 + quad) ^ swz) * 8];
        }
        // V^T B-fragments (shared across both q subgroups)
        short8 bV[4][2];
        #pragma unroll
        for (int dg = 0; dg < 4; ++dg) {
            const int vrow = dg * 16 + col;
            bV[dg][0] = *(const short8*)&Vs[cur][vrow][(quad ^ swz) * 8];
            bV[dg][1] = *(const short8*)&Vs[cur][vrow][((4 + quad) ^ swz) * 8];
        }

        #pragma unroll
        for (int qg = 0; qg < 2; ++qg) {
            const int qw = q0 + w * 32 + qg * 16;
            if (kt * 64 > qw + 15) continue;        // subgroup entirely future

            // S^T = K Q^T: C row=key(quad*4+r), col=q
            floatx4 sg[4];
            #pragma unroll
            for (int g = 0; g < 4; ++g) {
                floatx4 s = {0.f, 0.f, 0.f, 0.f};
                s = __builtin_amdgcn_mfma_f32_16x16x32_bf16(aK[g][0], bQ[qg][0], s, 0, 0, 0);
                s = __builtin_amdgcn_mfma_f32_16x16x32_bf16(aK[g][1], bQ[qg][1], s, 0, 0, 0);
                sg[g] = s;
            }

            const unsigned long long wr = Mw[cur][w * 32 + qg * 16 + col] >> (quad * 4);
            const unsigned wlo = (unsigned)wr, whi = (unsigned)(wr >> 32);
            const bool diag = (kt * 64 + 63 > qw);  // causal test needed for denom

            #pragma unroll
            for (int g = 0; g < 4; ++g) {
                float pv[4];
                #pragma unroll
                for (int r = 0; r < 4; ++r) {
                    float p = __builtin_amdgcn_exp2f(sg[g][r]);
                    if (diag) {
                        const int key = kt * 64 + g * 16 + quad * 4 + r;
                        p = (key <= qw + col) ? p : 0.f;
                    }
                    lacc[qg] += p;
                    const unsigned wsel = (g < 2) ? wlo : whi;
                    pv[r] = ((wsel >> ((g & 1) * 16 + r)) & 1u) ? 0.f : p;
                }
                const __hip_bfloat162 p01 = __float22bfloat162_rn({pv[0], pv[1]});
                const __hip_bfloat162 p23 = __float22bfloat162_rn({pv[2], pv[3]});
                uint2 pk;
                pk.x = *(const unsigned*)&p01;
                pk.y = *(const unsigned*)&p23;
                *(uint2*)&Pw[w][col][g * 16 + quad * 4] = pk;
            }

            // O += P V
            const short8 aP0 = *(const short8*)&Pw[w][col][quad * 8];
            const short8 aP1 = *(const short8*)&Pw[w][col][32 + quad * 8];
            #pragma unroll
            for (int dg = 0; dg < 4; ++dg) {
                Ov[qg][dg] = __builtin_amdgcn_mfma_f32_16x16x32_bf16(aP0, bV[dg][0], Ov[qg][dg], 0, 0, 0);
                Ov[qg][dg] = __builtin_amdgcn_mfma_f32_16x16x32_bf16(aP1, bV[dg][1], Ov[qg][dg], 0, 0, 0);
            }
        }
    }

    // epilogue: per subgroup, reduce l over quads, divide, store
    #pragma unroll
    for (int qg = 0; qg < 2; ++qg) {
        float l = lacc[qg];
        l += __shfl_xor(l, 16, 64);
        l += __shfl_xor(l, 32, 64);
        const float linv = 1.f / l;
        const int qw = q0 + w * 32 + qg * 16;
        #pragma unroll
        for (int r = 0; r < 4; ++r) {
            const float sc = __shfl(linv, quad * 4 + r, 64);
            const int q = qw + quad * 4 + r;
            bf16* orow = Aout + ((size_t)(b * kS + q)) * kDM + h * kDH;
            #pragma unroll
            for (int dg = 0; dg < 4; ++dg)
                orow[dg * 16 + col] = __float2bfloat16(Ov[qg][dg][r] * sc);
        }
    }
}

// ---------------------------------------------------------------------------
// out_mfma: Aout [8192][1024] bf16 @ WoT^T -> fp32 d_out. grid (8, 64).
// ---------------------------------------------------------------------------
__global__ __launch_bounds__(256)
void out_mfma(const bf16* __restrict__ A, const bf16* __restrict__ BT,
              float* __restrict__ Out)
{
    __shared__ __align__(16) unsigned short At[128][32];
    __shared__ __align__(16) unsigned short Bt[128][32];
    const int tid = threadIdx.x;
    const int w = tid >> 6, lane = tid & 63;
    const int quad = (tid >> 4) & 3, col = tid & 15;
    const int wm = w >> 1, wn = w & 1;
    const int n0 = blockIdx.x * 128;
    const int m0 = blockIdx.y * 128;

    const bf16* pA = A  + (size_t)(m0 + w * 32 + (lane >> 2)) * kDM + (lane & 3) * 8;
    const bf16* pB = BT + (size_t)(n0 + w * 32 + (lane >> 2)) * kDM + (lane & 3) * 8;
    unsigned short* lA = &At[w * 32][0];
    unsigned short* lB = &Bt[w * 32][0];

    floatx4 acc[4][4];
    #pragma unroll
    for (int i = 0; i < 4; ++i)
        #pragma unroll
        for (int j = 0; j < 4; ++j) acc[i][j] = (floatx4){0.f, 0.f, 0.f, 0.f};

    for (int k0 = 0; k0 < kDM; k0 += 32) {
        __syncthreads();
        gl_lds16(pA + k0, lA);
        gl_lds16(pA + k0 + 16 * kDM, lA + 16 * 32);
        gl_lds16(pB + k0, lB);
        gl_lds16(pB + k0 + 16 * kDM, lB + 16 * 32);
        __syncthreads();
        short8 aA[4], bB[4];
        #pragma unroll
        for (int i = 0; i < 4; ++i)
            aA[i] = *(const short8*)&At[wm * 64 + i * 16 + col][quad * 8];
        #pragma unroll
        for (int j = 0; j < 4; ++j)
            bB[j] = *(const short8*)&Bt[wn * 64 + j * 16 + col][quad * 8];
        #pragma unroll
        for (int i = 0; i < 4; ++i)
            #pragma unroll
            for (int j = 0; j < 4; ++j)
                acc[i][j] = __builtin_amdgcn_mfma_f32_16x16x32_bf16(aA[i], bB[j], acc[i][j], 0, 0, 0);
    }

    #pragma unroll
    for (int i = 0; i < 4; ++i)
        #pragma unroll
        for (int r = 0; r < 4; ++r) {
            const int m = m0 + wm * 64 + i * 16 + quad * 4 + r;
            #pragma unroll
            for (int j = 0; j < 4; ++j)
                Out[(size_t)m * kDM + n0 + wn * 64 + j * 16 + col] = acc[i][j][r];
        }
}

// ---------------------------------------------------------------------------
extern "C" void kernel_launch(void* const* d_in, const int* in_sizes, int n_in,
                              void* d_out, int out_size, void* d_ws, size_t ws_size,
                              hipStream_t stream)
{
    const float* Xq       = (const float*)d_in[0];
    // d_in[1] = mask_bef (causal, analytic — unused)
    const int*   mask_aft = (const int*)d_in[2];
    const float* Wq       = (const float*)d_in[3];
    const float* Wk       = (const float*)d_in[4];
    const float* Wv       = (const float*)d_in[5];
    const float* Wo       = (const float*)d_in[6];
    float* out = (float*)d_out;

    bf16* ws   = (bf16*)d_ws;
    bf16* Qbuf = ws;                           // [B,S,1024]
    bf16* Kbuf = ws + kHeadElems;
    bf16* Vbuf = ws + 2 * kHeadElems;
    bf16* Xbf  = ws + 3 * kHeadElems;          // aliased: Xbf -> Aout
    bf16* Aout = Xbf;
    bf16* WoT  = Qbuf;                         // overwrites Q slot AFTER attn

    unsigned long long* mp = (unsigned long long*)d_out;          // 512 KB
    bf16* WcatT = (bf16*)d_out + 262144;                          // [3072][1024], 6 MB
    bf16* VT    = (bf16*)((char*)d_out + 8u * 1024 * 1024);       // [bh][64][2048], 16 MB

    pack_mask<<<dim3(kS * 32 / 4), 256, 0, stream>>>(mask_aft, mp);
    conv_x   <<<dim3(4096), 256, 0, stream>>>(Xq, Xbf);
    conv_w3  <<<dim3(16, 16, 3), 256, 0, stream>>>(Wq, Wk, Wv, WcatT);
    qkv_mfma <<<dim3(24, 64), 256, 0, stream>>>(Xbf, WcatT, ws);
    vtrans   <<<dim3(32, 64), 256, 0, stream>>>(Vbuf, VT);
    attn_mfma<<<dim3(16, 64), 256, 0, stream>>>(Qbuf, Kbuf, VT, mp, Aout);
    conv_wT  <<<dim3(16, 16), 256, 0, stream>>>(Wo, WoT);         // Q slot now dead
    out_mfma <<<dim3(8, 64), 256, 0, stream>>>(Aout, WoT, out);
}

// Round 6
// 353.982 us; speedup vs baseline: 1.1157x; 1.1157x over previous
//
#include <hip/hip_runtime.h>
#include <hip/hip_bf16.h>

// Attention_2241972929086 — round 5: revert attn to round-3 structure (64-q blocks,
// single-buffer 26KB LDS, grid 2048 — occupancy is the binding resource) while
// keeping round-4's occupancy-neutral wins: row-major Q/K/V, exp2 softmax
// (scale folded into Q), cvt_pk P-packing, fused conv_w3, fused prep kernel.
// B=4 S=2048 D=1024 H=16 d=64.
// ws (bf16): Q[B,S,1024](prescaled x0.125*log2e) | K[B,S,1024] | V[B,S,1024] |
//            {Xbf -> Aout}[B,S,1024].  WoT overwrites Q slot AFTER attn.
// d_out temp: mp 512KB | WcatT 6MB @ +0.5MB | V^T 16MB @ +8MB — dead before out_mfma.

using bf16 = __hip_bfloat16;
typedef __attribute__((ext_vector_type(8))) short short8;
typedef __attribute__((ext_vector_type(4))) float floatx4;

#define kB 4
#define kS 2048
#define kDM 1024
#define kH 16
#define kDH 64
#define kHeadElems ((size_t)kB * kH * kS * kDH)   /* 8388608 */
#define STR 72
#define kQScale 0.1803368801f   /* 0.125 * log2(e): softmax via exp2 */

__device__ __forceinline__ unsigned short f2bf(float f) {
    union { float f; unsigned u; } x{f};
    unsigned r = x.u + 0x7fff + ((x.u >> 16) & 1);
    return (unsigned short)(r >> 16);
}
__device__ __forceinline__ void gl_lds16(const void* g, void* l) {
    __builtin_amdgcn_global_load_lds(
        (const __attribute__((address_space(1))) unsigned int*)g,
        (__attribute__((address_space(3))) unsigned int*)l, 16, 0, 0);
}

// ---------------------------------------------------------------------------
// prep: fused conv_x (blocks 0..4095) + pack_mask (blocks 4096..6143).
// conv_x: fp32 -> bf16, 8 elems/thread.  pack: bit = mask_aft[q][key] || key>q.
// ---------------------------------------------------------------------------
__global__ __launch_bounds__(256)
void prep(const float* __restrict__ X, bf16* __restrict__ Xb,
          const int* __restrict__ mask_aft, unsigned long long* __restrict__ mp)
{
    if (blockIdx.x < 4096) {
        const size_t i = ((size_t)blockIdx.x * 256 + threadIdx.x) * 8;
        const float4 a = *(const float4*)(X + i);
        const float4 b = *(const float4*)(X + i + 4);
        union { unsigned short u[8]; uint4 v; } o;
        o.u[0] = f2bf(a.x); o.u[1] = f2bf(a.y); o.u[2] = f2bf(a.z); o.u[3] = f2bf(a.w);
        o.u[4] = f2bf(b.x); o.u[5] = f2bf(b.y); o.u[6] = f2bf(b.z); o.u[7] = f2bf(b.w);
        *(uint4*)(Xb + i) = o.v;
    } else {
        const int wave = (blockIdx.x - 4096) * 4 + (threadIdx.x >> 6);  // 0..8191
        const int lane = threadIdx.x & 63;
        #pragma unroll
        for (int t = 0; t < 8; ++t) {
            const int widx = wave * 8 + t;          // 0..65535
            const int q = widx >> 5, w64 = widx & 31;
            const int key = w64 * 64 + lane;
            const int m = mask_aft[(size_t)q * kS + key];
            const unsigned long long bmask = __ballot(m != 0 || key > q);
            if (lane == 0) mp[widx] = bmask;
        }
    }
}

// ---------------------------------------------------------------------------
// conv_wT body: W [1024][1024] fp32 -> W^T bf16.
// ---------------------------------------------------------------------------
__device__ __forceinline__ void conv_wT_body(const float* __restrict__ W,
                                             bf16* __restrict__ WT)
{
    __shared__ unsigned short Ls[64][STR];
    const int k0 = blockIdx.x * 64, n0 = blockIdx.y * 64;
    const int tid = threadIdx.x;
    const int r16 = tid >> 4, c4 = (tid & 15) * 4;
    #pragma unroll
    for (int it = 0; it < 4; ++it) {
        const int r = it * 16 + r16;
        const float4 v = *(const float4*)(W + (size_t)(k0 + r) * kDM + n0 + c4);
        Ls[c4 + 0][r] = f2bf(v.x); Ls[c4 + 1][r] = f2bf(v.y);
        Ls[c4 + 2][r] = f2bf(v.z); Ls[c4 + 3][r] = f2bf(v.w);
    }
    __syncthreads();
    #pragma unroll
    for (int it = 0; it < 4; ++it) {
        const int rn = it * 16 + r16;
        ushort4 u;
        u.x = Ls[rn][c4 + 0]; u.y = Ls[rn][c4 + 1];
        u.z = Ls[rn][c4 + 2]; u.w = Ls[rn][c4 + 3];
        *(ushort4*)(WT + (size_t)(n0 + rn) * kDM + k0 + c4) = u;
    }
}

__global__ __launch_bounds__(256)
void conv_w3(const float* __restrict__ Wq, const float* __restrict__ Wk,
             const float* __restrict__ Wv, bf16* __restrict__ WT)
{
    const int z = blockIdx.z;
    const float* W = (z == 0) ? Wq : ((z == 1) ? Wk : Wv);
    conv_wT_body(W, WT + (size_t)z * kDM * kDM);
}

__global__ __launch_bounds__(256)
void conv_wT(const float* __restrict__ W, bf16* __restrict__ WT)
{
    conv_wT_body(W, WT);
}

// ---------------------------------------------------------------------------
// qkv_mfma: Xbf[8192][1024] @ WcatT[3072][1024]^T -> Q/K/V each [B,S,1024] bf16.
// Q pre-scaled by 0.125*log2(e).  grid (24, 64), block 256.
// ---------------------------------------------------------------------------
__global__ __launch_bounds__(256)
void qkv_mfma(const bf16* __restrict__ A, const bf16* __restrict__ BT,
              bf16* __restrict__ ws)
{
    __shared__ __align__(16) unsigned short At[128][32];
    __shared__ __align__(16) unsigned short Bt[128][32];
    const int tid = threadIdx.x;
    const int w = tid >> 6, lane = tid & 63;
    const int quad = (tid >> 4) & 3, col = tid & 15;
    const int wm = w >> 1, wn = w & 1;
    const int n0 = blockIdx.x * 128;
    const int m0 = blockIdx.y * 128;

    const bf16* pA = A  + (size_t)(m0 + w * 32 + (lane >> 2)) * kDM + (lane & 3) * 8;
    const bf16* pB = BT + (size_t)(n0 + w * 32 + (lane >> 2)) * kDM + (lane & 3) * 8;
    unsigned short* lA = &At[w * 32][0];
    unsigned short* lB = &Bt[w * 32][0];

    floatx4 acc[4][4];
    #pragma unroll
    for (int i = 0; i < 4; ++i)
        #pragma unroll
        for (int j = 0; j < 4; ++j) acc[i][j] = (floatx4){0.f, 0.f, 0.f, 0.f};

    for (int k0 = 0; k0 < kDM; k0 += 32) {
        __syncthreads();
        gl_lds16(pA + k0, lA);
        gl_lds16(pA + k0 + 16 * kDM, lA + 16 * 32);
        gl_lds16(pB + k0, lB);
        gl_lds16(pB + k0 + 16 * kDM, lB + 16 * 32);
        __syncthreads();
        short8 aA[4], bB[4];
        #pragma unroll
        for (int i = 0; i < 4; ++i)
            aA[i] = *(const short8*)&At[wm * 64 + i * 16 + col][quad * 8];
        #pragma unroll
        for (int j = 0; j < 4; ++j)
            bB[j] = *(const short8*)&Bt[wn * 64 + j * 16 + col][quad * 8];
        #pragma unroll
        for (int i = 0; i < 4; ++i)
            #pragma unroll
            for (int j = 0; j < 4; ++j)
                acc[i][j] = __builtin_amdgcn_mfma_f32_16x16x32_bf16(aA[i], bB[j], acc[i][j], 0, 0, 0);
    }

    const int p   = n0 >> 10;
    const int nn0 = n0 & 1023;
    const float scl = (p == 0) ? kQScale : 1.0f;
    bf16* Out = ws + (size_t)p * kHeadElems;
    #pragma unroll
    for (int i = 0; i < 4; ++i) {
        #pragma unroll
        for (int r = 0; r < 4; ++r) {
            const int m = m0 + wm * 64 + i * 16 + quad * 4 + r;
            bf16* base = Out + (size_t)m * kDM + nn0 + wn * 64 + col;
            #pragma unroll
            for (int j = 0; j < 4; ++j)
                base[j * 16] = __float2bfloat16(acc[i][j][r] * scl);
        }
    }
}

// ---------------------------------------------------------------------------
// vtrans: V [B,S,1024] (head h cols) -> V^T [bh][64][2048]. grid (32, 64).
// ---------------------------------------------------------------------------
__global__ __launch_bounds__(256)
void vtrans(const bf16* __restrict__ V, bf16* __restrict__ VT)
{
    const int bh = blockIdx.y;
    const int b = bh >> 4, h = bh & 15;
    const int s0 = blockIdx.x * 64;
    const bf16* src = V + ((size_t)b * kS) * kDM + h * kDH;
    bf16* dst = VT + (size_t)bh * kS * kDH;
    __shared__ unsigned short L[64][STR];
    const int tid = threadIdx.x;
    #pragma unroll
    for (int t = 0; t < 2; ++t) {
        const int idx = t * 256 + tid;
        const int r = idx >> 3, c8 = (idx & 7) * 8;
        *(uint4*)&L[r][c8] = *(const uint4*)(src + (size_t)(s0 + r) * kDM + c8);
    }
    __syncthreads();
    #pragma unroll
    for (int t = 0; t < 2; ++t) {
        const int idx = t * 256 + tid;
        const int d = idx >> 3, sc = (idx & 7) * 8;
        unsigned short tmp[8];
        #pragma unroll
        for (int e = 0; e < 8; ++e) tmp[e] = L[sc + e][d];
        *(uint4*)(dst + (size_t)d * kS + s0 + sc) = *(uint4*)tmp;
    }
}

// ---------------------------------------------------------------------------
// attn_mfma (round-3 structure): grid (32 qtiles, 64 bh), block 256 = 4 waves x 16 q.
// 64-q blocks, single-buffered 26KB LDS (6 blocks/CU — occupancy is the lever),
// S^T = K@Q^T MFMA, exp2 softmax, cvt_pk P-pack, combined causal|aft bitmask.
// ---------------------------------------------------------------------------
__global__ __launch_bounds__(256)
void attn_mfma(const bf16* __restrict__ Qb, const bf16* __restrict__ Kb,
               const bf16* __restrict__ VT, const unsigned long long* __restrict__ mp,
               bf16* __restrict__ Aout)
{
    const int bh = blockIdx.y;
    const int b = bh >> 4, h = bh & 15;
    const int qtile = 31 - blockIdx.x;          // heavy blocks first
    const int q0 = qtile * 64;
    const int tid = threadIdx.x;
    const int w    = tid >> 6;
    const int lane = tid & 63;
    const int quad = (tid >> 4) & 3;
    const int col  = tid & 15;

    const bf16* Qg  = Qb + ((size_t)b * kS) * kDM + h * kDH;   // row q at +q*1024
    const bf16* Kg  = Kb + ((size_t)b * kS) * kDM + h * kDH;
    const bf16* VTg = VT + (size_t)bh * kS * kDH;              // [64 d][2048 s]

    __shared__ __align__(16) unsigned short Ks[64][64];   // [key][d], swizzled chunks
    __shared__ __align__(16) unsigned short Vs[64][64];   // [d][key], swizzled chunks
    __shared__ __align__(16) unsigned short Pw[4][16][STR];
    __shared__ unsigned long long Mw[64];

    // Q B-fragments (n=q=col, k=d); Q pre-scaled by 0.125*log2e
    const int qw = q0 + w * 16;
    const short8 bQ0 = *(const short8*)(Qg + (size_t)(qw + col) * kDM + quad * 8);
    const short8 bQ1 = *(const short8*)(Qg + (size_t)(qw + col) * kDM + 32 + quad * 8);

    const int swz = col & 7;                    // read-side XOR swizzle
    const int sch = (lane & 7) ^ (lane >> 3);   // staging chunk

    floatx4 Ov[4] = {{0.f,0.f,0.f,0.f},{0.f,0.f,0.f,0.f},{0.f,0.f,0.f,0.f},{0.f,0.f,0.f,0.f}};
    float lacc = 0.f;

    for (int kt = 0; kt <= qtile; ++kt) {
        __syncthreads();
        // ---- stage K tile [64 keys][64 d] and V^T tile [64 d][64 keys] ----
        #pragma unroll
        for (int t = 0; t < 2; ++t) {
            const int rbase = (t * 4 + w) * 8;
            const int r = rbase + (lane >> 3);
            gl_lds16(Kg  + (size_t)(kt * 64 + r) * kDM + sch * 8, &Ks[rbase][0]);
            gl_lds16(VTg + (size_t)r * kS + kt * 64 + sch * 8,    &Vs[rbase][0]);
        }
        if (tid < 64) Mw[tid] = mp[(size_t)(q0 + tid) * 32 + kt];
        __syncthreads();

        // ---- S^T = K Q^T : A=K rows, B=Q rows; C: row=key(quad*4+r), col=q ----
        floatx4 sg[4];
        #pragma unroll
        for (int g = 0; g < 4; ++g) {
            const int krow = g * 16 + col;
            const short8 aK0 = *(const short8*)&Ks[krow][(quad ^ swz) * 8];
            const short8 aK1 = *(const short8*)&Ks[krow][((4 + quad) ^ swz) * 8];
            floatx4 s = {0.f, 0.f, 0.f, 0.f};
            s = __builtin_amdgcn_mfma_f32_16x16x32_bf16(aK0, bQ0, s, 0, 0, 0);
            s = __builtin_amdgcn_mfma_f32_16x16x32_bf16(aK1, bQ1, s, 0, 0, 0);
            sg[g] = s;
        }

        // ---- softmax numerator via exp2 (scale pre-folded); causal|aft bitmask ----
        const unsigned long long wr = Mw[w * 16 + col] >> (quad * 4);
        const unsigned wlo = (unsigned)wr, whi = (unsigned)(wr >> 32);
        const bool diag = (kt == qtile);

        #pragma unroll
        for (int g = 0; g < 4; ++g) {
            float pv[4];
            #pragma unroll
            for (int r = 0; r < 4; ++r) {
                float p = __builtin_amdgcn_exp2f(sg[g][r]);
                if (diag) {
                    const int key = kt * 64 + g * 16 + quad * 4 + r;
                    p = (key <= qw + col) ? p : 0.f;   // causal (exact denom)
                }
                lacc += p;
                const unsigned wsel = (g < 2) ? wlo : whi;
                pv[r] = ((wsel >> ((g & 1) * 16 + r)) & 1u) ? 0.f : p;
            }
            const __hip_bfloat162 p01 = __float22bfloat162_rn({pv[0], pv[1]});
            const __hip_bfloat162 p23 = __float22bfloat162_rn({pv[2], pv[3]});
            uint2 pk;
            pk.x = *(const unsigned*)&p01;
            pk.y = *(const unsigned*)&p23;
            *(uint2*)&Pw[w][col][g * 16 + quad * 4] = pk;
        }

        // ---- O += P V : A = P (wave-private LDS, A-layout), B = V^T tile ----
        const short8 aP0 = *(const short8*)&Pw[w][col][quad * 8];
        const short8 aP1 = *(const short8*)&Pw[w][col][32 + quad * 8];
        #pragma unroll
        for (int dg = 0; dg < 4; ++dg) {
            const int vrow = dg * 16 + col;
            const short8 bV0 = *(const short8*)&Vs[vrow][(quad ^ swz) * 8];
            const short8 bV1 = *(const short8*)&Vs[vrow][((4 + quad) ^ swz) * 8];
            Ov[dg] = __builtin_amdgcn_mfma_f32_16x16x32_bf16(aP0, bV0, Ov[dg], 0, 0, 0);
            Ov[dg] = __builtin_amdgcn_mfma_f32_16x16x32_bf16(aP1, bV1, Ov[dg], 0, 0, 0);
        }
    }

    // ---- l: reduce across quads; divide; store ----
    float l = lacc;
    l += __shfl_xor(l, 16, 64);
    l += __shfl_xor(l, 32, 64);
    const float linv = 1.f / l;
    #pragma unroll
    for (int r = 0; r < 4; ++r) {
        const float sc = __shfl(linv, quad * 4 + r, 64);
        const int q = qw + quad * 4 + r;
        bf16* orow = Aout + ((size_t)(b * kS + q)) * kDM + h * kDH;
        #pragma unroll
        for (int dg = 0; dg < 4; ++dg)
            orow[dg * 16 + col] = __float2bfloat16(Ov[dg][r] * sc);
    }
}

// ---------------------------------------------------------------------------
// out_mfma: Aout [8192][1024] bf16 @ WoT^T -> fp32 d_out. grid (8, 64).
// ---------------------------------------------------------------------------
__global__ __launch_bounds__(256)
void out_mfma(const bf16* __restrict__ A, const bf16* __restrict__ BT,
              float* __restrict__ Out)
{
    __shared__ __align__(16) unsigned short At[128][32];
    __shared__ __align__(16) unsigned short Bt[128][32];
    const int tid = threadIdx.x;
    const int w = tid >> 6, lane = tid & 63;
    const int quad = (tid >> 4) & 3, col = tid & 15;
    const int wm = w >> 1, wn = w & 1;
    const int n0 = blockIdx.x * 128;
    const int m0 = blockIdx.y * 128;

    const bf16* pA = A  + (size_t)(m0 + w * 32 + (lane >> 2)) * kDM + (lane & 3) * 8;
    const bf16* pB = BT + (size_t)(n0 + w * 32 + (lane >> 2)) * kDM + (lane & 3) * 8;
    unsigned short* lA = &At[w * 32][0];
    unsigned short* lB = &Bt[w * 32][0];

    floatx4 acc[4][4];
    #pragma unroll
    for (int i = 0; i < 4; ++i)
        #pragma unroll
        for (int j = 0; j < 4; ++j) acc[i][j] = (floatx4){0.f, 0.f, 0.f, 0.f};

    for (int k0 = 0; k0 < kDM; k0 += 32) {
        __syncthreads();
        gl_lds16(pA + k0, lA);
        gl_lds16(pA + k0 + 16 * kDM, lA + 16 * 32);
        gl_lds16(pB + k0, lB);
        gl_lds16(pB + k0 + 16 * kDM, lB + 16 * 32);
        __syncthreads();
        short8 aA[4], bB[4];
        #pragma unroll
        for (int i = 0; i < 4; ++i)
            aA[i] = *(const short8*)&At[wm * 64 + i * 16 + col][quad * 8];
        #pragma unroll
        for (int j = 0; j < 4; ++j)
            bB[j] = *(const short8*)&Bt[wn * 64 + j * 16 + col][quad * 8];
        #pragma unroll
        for (int i = 0; i < 4; ++i)
            #pragma unroll
            for (int j = 0; j < 4; ++j)
                acc[i][j] = __builtin_amdgcn_mfma_f32_16x16x32_bf16(aA[i], bB[j], acc[i][j], 0, 0, 0);
    }

    #pragma unroll
    for (int i = 0; i < 4; ++i)
        #pragma unroll
        for (int r = 0; r < 4; ++r) {
            const int m = m0 + wm * 64 + i * 16 + quad * 4 + r;
            #pragma unroll
            for (int j = 0; j < 4; ++j)
                Out[(size_t)m * kDM + n0 + wn * 64 + j * 16 + col] = acc[i][j][r];
        }
}

// ---------------------------------------------------------------------------
extern "C" void kernel_launch(void* const* d_in, const int* in_sizes, int n_in,
                              void* d_out, int out_size, void* d_ws, size_t ws_size,
                              hipStream_t stream)
{
    const float* Xq       = (const float*)d_in[0];
    // d_in[1] = mask_bef (causal, analytic — unused)
    const int*   mask_aft = (const int*)d_in[2];
    const float* Wq       = (const float*)d_in[3];
    const float* Wk       = (const float*)d_in[4];
    const float* Wv       = (const float*)d_in[5];
    const float* Wo       = (const float*)d_in[6];
    float* out = (float*)d_out;

    bf16* ws   = (bf16*)d_ws;
    bf16* Qbuf = ws;                           // [B,S,1024]
    bf16* Kbuf = ws + kHeadElems;
    bf16* Vbuf = ws + 2 * kHeadElems;
    bf16* Xbf  = ws + 3 * kHeadElems;          // aliased: Xbf -> Aout
    bf16* Aout = Xbf;
    bf16* WoT  = Qbuf;                         // overwrites Q slot AFTER attn

    unsigned long long* mp = (unsigned long long*)d_out;          // 512 KB
    bf16* WcatT = (bf16*)d_out + 262144;                          // [3072][1024], 6 MB
    bf16* VT    = (bf16*)((char*)d_out + 8u * 1024 * 1024);       // [bh][64][2048], 16 MB

    prep     <<<dim3(6144), 256, 0, stream>>>(Xq, Xbf, mask_aft, mp);
    conv_w3  <<<dim3(16, 16, 3), 256, 0, stream>>>(Wq, Wk, Wv, WcatT);
    qkv_mfma <<<dim3(24, 64), 256, 0, stream>>>(Xbf, WcatT, ws);
    vtrans   <<<dim3(32, 64), 256, 0, stream>>>(Vbuf, VT);
    attn_mfma<<<dim3(32, 64), 256, 0, stream>>>(Qbuf, Kbuf, VT, mp, Aout);
    conv_wT  <<<dim3(16, 16), 256, 0, stream>>>(Wo, WoT);         // Q slot now dead
    out_mfma <<<dim3(8, 64), 256, 0, stream>>>(Aout, WoT, out);
}